// Round 3
// baseline (2270.468 us; speedup 1.0000x reference)
//
#include <hip/hip_runtime.h>
#include <hip/hip_bf16.h>

typedef __bf16 bf16_t;
typedef __attribute__((ext_vector_type(8))) __bf16 bf16x8;
typedef __attribute__((ext_vector_type(4))) float f32x4;

#define O_N 100000
#define T_N 200000
#define LDA 72   // padded LDS row stride (elems): 144B -> 2-way bank aliasing (free, m136)

__device__ __forceinline__ bf16x8 cvt8(const float* p) {
    f32x4 a = *(const f32x4*)p;
    f32x4 b = *(const f32x4*)(p + 4);
    bf16x8 v;
    v[0] = (bf16_t)a[0]; v[1] = (bf16_t)a[1]; v[2] = (bf16_t)a[2]; v[3] = (bf16_t)a[3];
    v[4] = (bf16_t)b[0]; v[5] = (bf16_t)b[1]; v[6] = (bf16_t)b[2]; v[7] = (bf16_t)b[3];
    return v;
}

// MODE 1: A = gather-concat(objF[s]|predF|objF[o]) f32->bf16 -> CoutB = h (bf16)
// MODE 2: A = h (bf16); epilogue: col<512 atomic pooled[s], 512..639 -> newp(f32), >=640 atomic pooled[o]
// MODE 3: A = poolIn(f32)/max(counts,1) -> bf16 (fused div) -> CoutB = t3 (bf16)
// MODE 4: A = t3 (bf16) -> CoutF = new_obj (f32)
template<int MODE, int N, int K>
__launch_bounds__(256)
__global__ void gemm_k(const bf16_t* __restrict__ A,
                       const float*  __restrict__ AobjF,
                       const float*  __restrict__ ApredF,
                       const int*    __restrict__ edges,
                       const float*  __restrict__ poolIn,
                       const float*  __restrict__ countsIn,
                       const bf16_t* __restrict__ Bt,     // N x K row-major bf16
                       const float*  __restrict__ bias,   // length N, f32
                       bf16_t*       __restrict__ CoutB,
                       float*        __restrict__ CoutF,  // MODE2: newp base; MODE4: new_obj
                       float*        __restrict__ pooled,
                       int M)
{
    __shared__ bf16_t lA[128 * LDA];
    __shared__ bf16_t lB[128 * LDA];
    __shared__ int sIdxL[128], oIdxL[128];

    const int tid  = threadIdx.x;
    const int lane = tid & 63;
    const int wv   = tid >> 6;
    const int wr   = (wv >> 1) * 64;   // wave row base in 128-tile
    const int wc   = (wv & 1) * 64;    // wave col base
    const int fr   = lane & 15;        // m/n within 16-tile
    const int fk   = (lane >> 4) * 8;  // k offset within 32
    const int mbase = blockIdx.y * 128;
    const int nbase = blockIdx.x * 128;

    if constexpr (MODE == 1 || MODE == 2) {
        if (tid < 128) {
            int g = mbase + tid; if (g > M - 1) g = M - 1;
            sIdxL[tid] = edges[2 * g];
            oIdxL[tid] = edges[2 * g + 1];
        }
    }
    __syncthreads();

    f32x4 acc[4][4];
    #pragma unroll
    for (int i = 0; i < 4; i++)
        #pragma unroll
        for (int j = 0; j < 4; j++)
            acc[i][j] = (f32x4){0.f, 0.f, 0.f, 0.f};

    const int KT = K / 64;
    for (int kt = 0; kt < KT; ++kt) {
        const int k0 = kt * 64;
        // ---- stage A tile (128 rows x 64 k) : 8 elems/thread x4 ----
        #pragma unroll
        for (int t = 0; t < 4; ++t) {
            int e   = t * 2048 + tid * 8;
            int row = e >> 6;
            int col = e & 63;
            int grow = mbase + row; if (grow > M - 1) grow = M - 1;
            bf16x8 v;
            if constexpr (MODE == 1) {
                int k = k0 + col;  // 64-chunk lies in one 128-wide segment
                const float* gp;
                if (k < 128)      gp = AobjF  + (size_t)sIdxL[row] * 128 + k;
                else if (k < 256) gp = ApredF + (size_t)grow * 128 + (k - 128);
                else              gp = AobjF  + (size_t)oIdxL[row] * 128 + (k - 256);
                v = cvt8(gp);
            } else if constexpr (MODE == 3) {
                const float* pr = poolIn + (size_t)grow * 512 + k0 + col;
                float c = countsIn[grow]; c = c > 1.f ? c : 1.f;
                float rc = 1.f / c;
                f32x4 p0 = *(const f32x4*)pr;
                f32x4 p1 = *(const f32x4*)(pr + 4);
                v[0] = (bf16_t)(p0[0] * rc); v[1] = (bf16_t)(p0[1] * rc);
                v[2] = (bf16_t)(p0[2] * rc); v[3] = (bf16_t)(p0[3] * rc);
                v[4] = (bf16_t)(p1[0] * rc); v[5] = (bf16_t)(p1[1] * rc);
                v[6] = (bf16_t)(p1[2] * rc); v[7] = (bf16_t)(p1[3] * rc);
            } else {
                v = *(const bf16x8*)(A + (size_t)grow * K + k0 + col);
            }
            *(bf16x8*)&lA[row * LDA + col] = v;
        }
        // ---- stage B tile (128 n x 64 k), bf16 source ----
        #pragma unroll
        for (int t = 0; t < 4; ++t) {
            int e   = t * 2048 + tid * 8;
            int row = e >> 6;
            int col = e & 63;
            bf16x8 v = *(const bf16x8*)(Bt + (size_t)(nbase + row) * K + k0 + col);
            *(bf16x8*)&lB[row * LDA + col] = v;
        }
        __syncthreads();

        #pragma unroll
        for (int ks = 0; ks < 64; ks += 32) {
            bf16x8 af[4], bf[4];
            #pragma unroll
            for (int i = 0; i < 4; i++)
                af[i] = *(const bf16x8*)&lA[(wr + i * 16 + fr) * LDA + ks + fk];
            #pragma unroll
            for (int j = 0; j < 4; j++)
                bf[j] = *(const bf16x8*)&lB[(wc + j * 16 + fr) * LDA + ks + fk];
            #pragma unroll
            for (int i = 0; i < 4; i++)
                #pragma unroll
                for (int j = 0; j < 4; j++)
                    acc[i][j] = __builtin_amdgcn_mfma_f32_16x16x32_bf16(
                        af[i], bf[j], acc[i][j], 0, 0, 0);
        }
        __syncthreads();
    }

    // epilogue: D col = lane&15, row = (lane>>4)*4 + reg  [m89-verified]
    #pragma unroll
    for (int j = 0; j < 4; j++) {
        int col = nbase + wc + j * 16 + fr;
        float bval = bias[col];
        #pragma unroll
        for (int i = 0; i < 4; i++) {
            #pragma unroll
            for (int r = 0; r < 4; r++) {
                int rl   = wr + i * 16 + (lane >> 4) * 4 + r;
                int grow = mbase + rl;
                if (grow >= M) continue;
                float v = acc[i][j][r] + bval;
                v = v > 0.f ? v : 0.f;
                if constexpr (MODE == 2) {
                    if (col < 512)      unsafeAtomicAdd(&pooled[(size_t)sIdxL[rl] * 512 + col], v);
                    else if (col < 640) CoutF[(size_t)grow * 128 + (col - 512)] = v;
                    else                unsafeAtomicAdd(&pooled[(size_t)oIdxL[rl] * 512 + (col - 640)], v);
                } else if constexpr (MODE == 4) {
                    CoutF[(size_t)grow * N + col] = v;
                } else {
                    CoutB[(size_t)grow * N + col] = (bf16_t)v;
                }
            }
        }
    }
}

// f32 in (K x N row-major) -> bf16 out (N x K row-major)
__global__ void transpose_k(const float* __restrict__ in, bf16_t* __restrict__ out,
                            int K, int N) {
    int idx = blockIdx.x * 256 + threadIdx.x;
    if (idx < K * N) {
        int k = idx / N, n = idx - k * N;
        out[n * K + k] = (bf16_t)in[idx];
    }
}

__global__ void counts_k(const int* __restrict__ edges, float* __restrict__ counts) {
    int t = blockIdx.x * 256 + threadIdx.x;
    if (t < T_N) {
        unsafeAtomicAdd(&counts[edges[2 * t]],     1.f);
        unsafeAtomicAdd(&counts[edges[2 * t + 1]], 1.f);
    }
}

extern "C" void kernel_launch(void* const* d_in, const int* in_sizes, int n_in,
                              void* d_out, int out_size, void* d_ws, size_t ws_size,
                              hipStream_t stream) {
    const float* obj  = (const float*)d_in[0];
    const float* pred = (const float*)d_in[1];
    const int*   edges= (const int*)d_in[2];
    const float* W1 = (const float*)d_in[3];
    const float* b1 = (const float*)d_in[4];
    const float* W2 = (const float*)d_in[5];
    const float* b2 = (const float*)d_in[6];
    const float* W3 = (const float*)d_in[7];
    const float* b3 = (const float*)d_in[8];
    const float* W4 = (const float*)d_in[9];
    const float* b4 = (const float*)d_in[10];
    float* out = (float*)d_out;   // [new_obj O_N*128 | new_p T_N*128], f32

    char* ws = (char*)d_ws;
    // layout (bytes), peak ~309.9 MB:
    //   pooled f32 O*512*4 = 204,800,000                      @ 0
    //   counts f32 O*4     =     400,000                      @ 204,800,000
    //   region1 (h chunk 100k x 512 bf16 | later t3) 102.4MB  @ 205,200,128
    //   W1t..W4t bf16 ~2.23MB                                 @ 307,600,128
    float*  pooled = (float*)(ws + 0);
    float*  counts = (float*)(ws + 204800000);
    bf16_t* hbuf   = (bf16_t*)(ws + 205200128);
    bf16_t* t3     = hbuf;                         // reused after gemm2 chunks
    bf16_t* W1t    = (bf16_t*)(ws + 307600128);
    bf16_t* W2t    = (bf16_t*)(ws + 307993344);
    bf16_t* W3t    = (bf16_t*)(ws + 309172992);
    bf16_t* W4t    = (bf16_t*)(ws + 309697280);

    hipMemsetAsync(pooled, 0, 205200000, stream);   // pooled + counts

    transpose_k<<<(384 * 512  + 255) / 256, 256, 0, stream>>>(W1, W1t, 384, 512);
    transpose_k<<<(512 * 1152 + 255) / 256, 256, 0, stream>>>(W2, W2t, 512, 1152);
    transpose_k<<<(512 * 512  + 255) / 256, 256, 0, stream>>>(W3, W3t, 512, 512);
    transpose_k<<<(512 * 128  + 255) / 256, 256, 0, stream>>>(W4, W4t, 512, 128);
    counts_k<<<(T_N + 255) / 256, 256, 0, stream>>>(edges, counts);

    // gemm1+gemm2 in two 100k-row chunks (pooled is atomic-accumulated, so safe)
    for (int c = 0; c < 2; ++c) {
        const int row0 = c * 100000;
        gemm_k<1, 512, 384><<<dim3(4, 782), 256, 0, stream>>>(
            nullptr, obj, pred + (size_t)row0 * 128, edges + 2 * row0,
            nullptr, nullptr, W1t, b1, hbuf, nullptr, nullptr, 100000);
        gemm_k<2, 1152, 512><<<dim3(9, 782), 256, 0, stream>>>(
            hbuf, nullptr, nullptr, edges + 2 * row0,
            nullptr, nullptr, W2t, b2, nullptr,
            out + (size_t)O_N * 128 + (size_t)row0 * 128, pooled, 100000);
    }
    // t3 = relu((pooled/max(counts,1)) @ W3 + b3)   (div fused into A-stage)
    gemm_k<3, 512, 512><<<dim3(4, 782), 256, 0, stream>>>(
        nullptr, nullptr, nullptr, nullptr, pooled, counts,
        W3t, b3, t3, nullptr, nullptr, O_N);
    // new_obj = relu(t3 @ W4 + b4)
    gemm_k<4, 128, 512><<<dim3(1, 782), 256, 0, stream>>>(
        t3, nullptr, nullptr, nullptr, nullptr, nullptr,
        W4t, b4, nullptr, out, nullptr, O_N);
}

// Round 4
// 2183.002 us; speedup vs baseline: 1.0401x; 1.0401x over previous
//
#include <hip/hip_runtime.h>
#include <hip/hip_bf16.h>

typedef __bf16 bf16_t;
typedef __attribute__((ext_vector_type(8))) __bf16 bf16x8;
typedef __attribute__((ext_vector_type(4))) float f32x4;

#define O_N 100000
#define T_N 200000
#define LDA 72   // padded LDS row stride (elems): 144B -> 2-way bank aliasing (free, m136)

__device__ __forceinline__ bf16x8 cvt8(const float* p) {
    f32x4 a = *(const f32x4*)p;
    f32x4 b = *(const f32x4*)(p + 4);
    bf16x8 v;
    v[0] = (bf16_t)a[0]; v[1] = (bf16_t)a[1]; v[2] = (bf16_t)a[2]; v[3] = (bf16_t)a[3];
    v[4] = (bf16_t)b[0]; v[5] = (bf16_t)b[1]; v[6] = (bf16_t)b[2]; v[7] = (bf16_t)b[3];
    return v;
}

// MODE 1: A = gather-concat(objF[s]|predF|objF[o]) f32->bf16 -> CoutB = h (bf16)
// MODE 2: A = h (bf16); MFMA operand-swapped (transposed C in regs):
//         lane holds 4 consecutive n-cols for one edge row ->
//         n-blocks 0-3: pk_add_bf16 scatter to pooledB[s]; block 4: f32x4 -> newp;
//         blocks 5-8: pk_add_bf16 scatter to pooledB[o].  CoutB = pooledB.
// MODE 3: A = pooledB (bf16) * 1/max(counts,1) (fused div) -> CoutB = t3 (bf16)
// MODE 4: A = t3 (bf16) -> CoutF = new_obj (f32)
template<int MODE, int N, int K>
__launch_bounds__(256)
__global__ void gemm_k(const bf16_t* __restrict__ A,
                       const float*  __restrict__ AobjF,
                       const float*  __restrict__ ApredF,
                       const int*    __restrict__ edges,
                       const float*  __restrict__ countsIn,
                       const bf16_t* __restrict__ Bt,     // N x K row-major bf16
                       const float*  __restrict__ bias,   // length N, f32
                       bf16_t*       __restrict__ CoutB,  // MODE1: h, MODE2: pooledB, MODE3: t3
                       float*        __restrict__ CoutF,  // MODE2: newp base; MODE4: new_obj
                       int M)
{
    __shared__ bf16_t lA[128 * LDA];
    __shared__ bf16_t lB[128 * LDA];
    __shared__ int sIdxL[128], oIdxL[128];

    const int tid  = threadIdx.x;
    const int lane = tid & 63;
    const int wv   = tid >> 6;
    const int wr   = (wv >> 1) * 64;   // wave row base in 128-tile
    const int wc   = (wv & 1) * 64;    // wave col base
    const int fr   = lane & 15;        // m/n within 16-tile
    const int fk   = (lane >> 4) * 8;  // k offset within 32
    const int mbase = blockIdx.y * 128;
    const int nbase = blockIdx.x * 128;

    if constexpr (MODE == 1 || MODE == 2) {
        if (tid < 128) {
            int g = mbase + tid; if (g > M - 1) g = M - 1;
            sIdxL[tid] = edges[2 * g];
            oIdxL[tid] = edges[2 * g + 1];
        }
    }
    __syncthreads();

    f32x4 acc[4][4];
    #pragma unroll
    for (int i = 0; i < 4; i++)
        #pragma unroll
        for (int j = 0; j < 4; j++)
            acc[i][j] = (f32x4){0.f, 0.f, 0.f, 0.f};

    const int KT = K / 64;
    for (int kt = 0; kt < KT; ++kt) {
        const int k0 = kt * 64;
        // ---- stage A tile (128 rows x 64 k) : 8 elems/thread x4 ----
        #pragma unroll
        for (int t = 0; t < 4; ++t) {
            int e   = t * 2048 + tid * 8;
            int row = e >> 6;
            int col = e & 63;
            int grow = mbase + row; if (grow > M - 1) grow = M - 1;
            bf16x8 v;
            if constexpr (MODE == 1) {
                int k = k0 + col;  // 64-chunk lies in one 128-wide segment
                const float* gp;
                if (k < 128)      gp = AobjF  + (size_t)sIdxL[row] * 128 + k;
                else if (k < 256) gp = ApredF + (size_t)grow * 128 + (k - 128);
                else              gp = AobjF  + (size_t)oIdxL[row] * 128 + (k - 256);
                v = cvt8(gp);
            } else if constexpr (MODE == 3) {
                const bf16_t* pr = A + (size_t)grow * 512 + k0 + col;
                float c = countsIn[grow]; c = c > 1.f ? c : 1.f;
                float rc = 1.f / c;
                bf16x8 raw = *(const bf16x8*)pr;
                #pragma unroll
                for (int l = 0; l < 8; l++) v[l] = (bf16_t)((float)raw[l] * rc);
            } else {
                v = *(const bf16x8*)(A + (size_t)grow * K + k0 + col);
            }
            *(bf16x8*)&lA[row * LDA + col] = v;
        }
        // ---- stage B tile (128 n x 64 k), bf16 source ----
        #pragma unroll
        for (int t = 0; t < 4; ++t) {
            int e   = t * 2048 + tid * 8;
            int row = e >> 6;
            int col = e & 63;
            bf16x8 v = *(const bf16x8*)(Bt + (size_t)(nbase + row) * K + k0 + col);
            *(bf16x8*)&lB[row * LDA + col] = v;
        }
        __syncthreads();

        #pragma unroll
        for (int ks = 0; ks < 64; ks += 32) {
            bf16x8 af[4], bf[4];
            #pragma unroll
            for (int i = 0; i < 4; i++)
                af[i] = *(const bf16x8*)&lA[(wr + i * 16 + fr) * LDA + ks + fk];
            #pragma unroll
            for (int j = 0; j < 4; j++)
                bf[j] = *(const bf16x8*)&lB[(wc + j * 16 + fr) * LDA + ks + fk];
            #pragma unroll
            for (int i = 0; i < 4; i++)
                #pragma unroll
                for (int j = 0; j < 4; j++) {
                    if constexpr (MODE == 2)
                        // swapped operands: acc holds C^T -> lane owns 4 consecutive n
                        acc[i][j] = __builtin_amdgcn_mfma_f32_16x16x32_bf16(
                            bf[j], af[i], acc[i][j], 0, 0, 0);
                    else
                        acc[i][j] = __builtin_amdgcn_mfma_f32_16x16x32_bf16(
                            af[i], bf[j], acc[i][j], 0, 0, 0);
                }
        }
        __syncthreads();
    }

    if constexpr (MODE == 2) {
        // transposed D: col(lane&15)=m (edge row), row((lane>>4)*4+r)=n (out col)
        const bool isNewp = (nbase == 512);
        const bool isS    = (nbase < 512);
        const int* idxArr = isS ? sIdxL : oIdxL;
        const int  cb     = isS ? nbase : (nbase - 640);   // pooled col base
        #pragma unroll
        for (int j = 0; j < 4; j++) {
            int nl = wc + j * 16 + (lane >> 4) * 4;        // 4-aligned col offset
            f32x4 bv = *(const f32x4*)&bias[nbase + nl];
            #pragma unroll
            for (int i = 0; i < 4; i++) {
                int ml   = wr + i * 16 + fr;
                int grow = mbase + ml;
                if (grow >= M) continue;
                float v0 = acc[i][j][0] + bv[0]; v0 = v0 > 0.f ? v0 : 0.f;
                float v1 = acc[i][j][1] + bv[1]; v1 = v1 > 0.f ? v1 : 0.f;
                float v2 = acc[i][j][2] + bv[2]; v2 = v2 > 0.f ? v2 : 0.f;
                float v3 = acc[i][j][3] + bv[3]; v3 = v3 > 0.f ? v3 : 0.f;
                if (isNewp) {
                    f32x4 o = {v0, v1, v2, v3};
                    *(f32x4*)&CoutF[(size_t)grow * 128 + nl] = o;   // nbase+nl-512 == nl
                } else {
                    int idx = idxArr[ml];
                    __hip_bfloat162 p0, p1;
                    p0.x = __float2bfloat16(v0); p0.y = __float2bfloat16(v1);
                    p1.x = __float2bfloat16(v2); p1.y = __float2bfloat16(v3);
                    __hip_bfloat162* base =
                        (__hip_bfloat162*)(CoutB + (size_t)idx * 512 + cb + nl);
                    unsafeAtomicAdd(base,     p0);
                    unsafeAtomicAdd(base + 1, p1);
                }
            }
        }
    } else {
        // normal D: col(lane&15)=n, row((lane>>4)*4+r)=m  [m89-verified]
        #pragma unroll
        for (int j = 0; j < 4; j++) {
            int col = nbase + wc + j * 16 + fr;
            float bval = bias[col];
            #pragma unroll
            for (int i = 0; i < 4; i++) {
                #pragma unroll
                for (int r = 0; r < 4; r++) {
                    int rl   = wr + i * 16 + (lane >> 4) * 4 + r;
                    int grow = mbase + rl;
                    if (grow >= M) continue;
                    float v = acc[i][j][r] + bval;
                    v = v > 0.f ? v : 0.f;
                    if constexpr (MODE == 4)
                        CoutF[(size_t)grow * N + col] = v;
                    else
                        CoutB[(size_t)grow * N + col] = (bf16_t)v;
                }
            }
        }
    }
}

// f32 in (K x N row-major) -> bf16 out (N x K row-major)
__global__ void transpose_k(const float* __restrict__ in, bf16_t* __restrict__ out,
                            int K, int N) {
    int idx = blockIdx.x * 256 + threadIdx.x;
    if (idx < K * N) {
        int k = idx / N, n = idx - k * N;
        out[n * K + k] = (bf16_t)in[idx];
    }
}

__global__ void counts_k(const int* __restrict__ edges, float* __restrict__ counts) {
    int t = blockIdx.x * 256 + threadIdx.x;
    if (t < T_N) {
        unsafeAtomicAdd(&counts[edges[2 * t]],     1.f);
        unsafeAtomicAdd(&counts[edges[2 * t + 1]], 1.f);
    }
}

extern "C" void kernel_launch(void* const* d_in, const int* in_sizes, int n_in,
                              void* d_out, int out_size, void* d_ws, size_t ws_size,
                              hipStream_t stream) {
    const float* obj  = (const float*)d_in[0];
    const float* pred = (const float*)d_in[1];
    const int*   edges= (const int*)d_in[2];
    const float* W1 = (const float*)d_in[3];
    const float* b1 = (const float*)d_in[4];
    const float* W2 = (const float*)d_in[5];
    const float* b2 = (const float*)d_in[6];
    const float* W3 = (const float*)d_in[7];
    const float* b3 = (const float*)d_in[8];
    const float* W4 = (const float*)d_in[9];
    const float* b4 = (const float*)d_in[10];
    float* out = (float*)d_out;   // [new_obj O_N*128 | new_p T_N*128], f32

    char* ws = (char*)d_ws;
    // layout (bytes), peak ~207.5 MB:
    //   pooledB bf16 O*512*2 = 102,400,000                    @ 0
    //   counts  f32  O*4     =     400,000                    @ 102,400,000
    //   region1 (h chunk 100k x 512 bf16 | later t3) 102.4MB  @ 102,800,128
    //   W1t..W4t bf16 ~2.23MB                                 @ 205,200,128
    bf16_t* pooledB = (bf16_t*)(ws + 0);
    float*  counts  = (float*)(ws + 102400000);
    bf16_t* hbuf    = (bf16_t*)(ws + 102800128);
    bf16_t* t3      = hbuf;                        // reused after gemm2 chunks
    bf16_t* W1t     = (bf16_t*)(ws + 205200128);
    bf16_t* W2t     = (bf16_t*)(ws + 205593344);
    bf16_t* W3t     = (bf16_t*)(ws + 206772992);
    bf16_t* W4t     = (bf16_t*)(ws + 207297280);

    hipMemsetAsync(pooledB, 0, 102800000, stream);   // pooledB + counts

    transpose_k<<<(384 * 512  + 255) / 256, 256, 0, stream>>>(W1, W1t, 384, 512);
    transpose_k<<<(512 * 1152 + 255) / 256, 256, 0, stream>>>(W2, W2t, 512, 1152);
    transpose_k<<<(512 * 512  + 255) / 256, 256, 0, stream>>>(W3, W3t, 512, 512);
    transpose_k<<<(512 * 128  + 255) / 256, 256, 0, stream>>>(W4, W4t, 512, 128);
    counts_k<<<(T_N + 255) / 256, 256, 0, stream>>>(edges, counts);

    // gemm1+gemm2 in two 100k-row chunks (pooledB is atomic-accumulated, so safe)
    for (int c = 0; c < 2; ++c) {
        const int row0 = c * 100000;
        gemm_k<1, 512, 384><<<dim3(4, 782), 256, 0, stream>>>(
            nullptr, obj, pred + (size_t)row0 * 128, edges + 2 * row0,
            nullptr, W1t, b1, hbuf, nullptr, 100000);
        gemm_k<2, 1152, 512><<<dim3(9, 782), 256, 0, stream>>>(
            hbuf, nullptr, nullptr, edges + 2 * row0,
            nullptr, W2t, b2, pooledB,
            out + (size_t)O_N * 128 + (size_t)row0 * 128, 100000);
    }
    // t3 = relu((pooledB/max(counts,1)) @ W3 + b3)   (div fused into A-stage)
    gemm_k<3, 512, 512><<<dim3(4, 782), 256, 0, stream>>>(
        pooledB, nullptr, nullptr, nullptr, counts,
        W3t, b3, t3, nullptr, O_N);
    // new_obj = relu(t3 @ W4 + b4)
    gemm_k<4, 128, 512><<<dim3(1, 782), 256, 0, stream>>>(
        t3, nullptr, nullptr, nullptr, nullptr,
        W4t, b4, nullptr, out, O_N);
}